// Round 3
// baseline (108.844 us; speedup 1.0000x reference)
//
#include <hip/hip_runtime.h>
#include <hip/hip_bf16.h>
#include <cstdint>

#define B_ 4096
#define D_ 256
#define M_ 60
#define NT_ 64          // 64-tiles per dimension
#define NBLK 2080       // NT_*(NT_+1)/2 upper-triangle tiles
#define BM 64
#define BK 64           // bf16 elements per K-step (128 bytes/row)

typedef unsigned long long u64;
typedef short bf16x8 __attribute__((ext_vector_type(8)));   // 8 bf16 = 4 VGPRs
typedef float f32x4 __attribute__((ext_vector_type(4)));

__device__ __forceinline__ unsigned short f2bf(float x) {
    __hip_bfloat16 b = __float2bfloat16(x);
    return __builtin_bit_cast(unsigned short, b);
}

// ---------- prep: bf16 cast of raw rep, inv-norm*sqrt(10), code masks (coalesced, once) ----------
__global__ __launch_bounds__(256) void prep_kernel(
    const float* __restrict__ rep, const int* __restrict__ codes,
    unsigned short* __restrict__ nb, float* __restrict__ invs,
    u64* __restrict__ lo, u64* __restrict__ hi, int* __restrict__ cnt,
    unsigned int* __restrict__ done) {
    const int w = threadIdx.x >> 6;
    const int lane = threadIdx.x & 63;
    const int row = blockIdx.x * 4 + w;

    // zero the last-block-done counter (workspace is re-poisoned each iteration);
    // agent-scope so the later fused_kernel atomics on any XCD see a clean 0.
    if (blockIdx.x == 0 && threadIdx.x == 0)
        __hip_atomic_store(done, 0u, __ATOMIC_RELAXED, __HIP_MEMORY_SCOPE_AGENT);

    float4 v = ((const float4*)(rep + (size_t)row * D_))[lane];
    float ss = v.x * v.x + v.y * v.y + v.z * v.z + v.w * v.w;
#pragma unroll
    for (int off = 32; off > 0; off >>= 1) ss += __shfl_down(ss, off);
    ss = __shfl(ss, 0);

    // store RAW bf16 (normalization folded into epilogue scale)
    ushort4 o;
    o.x = f2bf(v.x); o.y = f2bf(v.y); o.z = f2bf(v.z); o.w = f2bf(v.w);
    ((ushort4*)(nb + (size_t)row * D_))[lane] = o;

    // code membership mask via wave-OR reduction
    u64 l = 0, h = 0;
    if (lane < M_) {
        int c = codes[row * M_ + lane];
        if (c < 64) l = 1ull << c;
        else        h = 1ull << (c - 64);
    }
#pragma unroll
    for (int off = 32; off > 0; off >>= 1) {
        l |= __shfl_down(l, off);
        h |= __shfl_down(h, off);
    }
    if (lane == 0) {
        invs[row] = (1.0f / sqrtf(ss)) * 3.16227766016838f;  // inv_norm * sqrt(1/T)
        lo[row] = l; hi[row] = h;
        cnt[row] = __popcll(l) + __popcll(h);
    }
}

// ---------- fused: 64x64 tiles, 2080 blocks (8.1 blocks/CU), 4 waves, store partials ----------
// Wave w owns a 32x32 quadrant: wr=w>>1 row half, wc=w&1 col half.
// Last block to finish reduces all partials and writes the loss (no separate finalize launch).
// ALL cross-block communication uses agent-scope atomics: gfx950 per-XCD L2s are not
// coherent, and plain-store + __threadfence proved insufficient (R2 tripwire: graph
// output exact, fresh single-launch NaN == consumer read stale/poisoned partials).
__global__ __launch_bounds__(256) void fused_kernel(
    const unsigned short* __restrict__ Nb, const float* __restrict__ invs,
    const u64* __restrict__ lo, const u64* __restrict__ hi, const int* __restrict__ cnt,
    double* __restrict__ partials /* NBLK x 8 doubles (64B stride) */,
    unsigned int* __restrict__ done, float* __restrict__ out) {
    // 8 KB per operand tile: 64 rows x 64 bf16 (128 B/row), XOR-swizzled 16B chunks
    __shared__ __attribute__((aligned(16))) char AsB[BM * BK * 2];
    __shared__ __attribute__((aligned(16))) char BsB[BM * BK * 2];
    __shared__ float redT[4], redPe[4], redPs[4];
    __shared__ int redC[4];
    __shared__ int isLast;

    const int tid = threadIdx.x;
    const int lane = tid & 63;
    const int w = tid >> 6;          // 0..3
    const int wr = w >> 1, wc = w & 1;
    const int quad = lane >> 4;
    const int l15 = lane & 15;
    const int l7 = lane & 7;

    // block -> (bi, bj) with bj >= bi
    int q = blockIdx.x, bi = 0;
    while (q >= NT_ - bi) { q -= NT_ - bi; bi++; }
    const int bj = bi + q;
    const int rowA = bi * BM, rowB = bj * BM;

    // hoist column-side epilogue data
    int colg[2]; u64 jl[2], jh[2]; int jc[2]; float ib[2];
#pragma unroll
    for (int nt = 0; nt < 2; nt++) {
        int cg = rowB + wc * 32 + nt * 16 + l15;
        colg[nt] = cg; jl[nt] = lo[cg]; jh[nt] = hi[cg]; jc[nt] = cnt[cg];
        ib[nt] = invs[cg];
    }

    f32x4 accf[2][2] = {};

    for (int k0 = 0; k0 < D_; k0 += BK) {
        __syncthreads();
        // stage A and B tiles (8 KB each = 8 regions x 1024 B), 2 shots x 4 waves per operand
        // physical chunk P = region*64 + lane (0..511); row = P>>3, pc = P&7, c = pc ^ (row&7)
#pragma unroll
        for (int it = 0; it < 2; it++) {
            int region = it * 4 + w;          // 0..7
            int P = region * 64 + lane;       // 0..511
            int row = P >> 3;
            int c = (P & 7) ^ (row & 7);
            const unsigned short* gA = Nb + (size_t)(rowA + row) * D_ + k0 + c * 8;
            const unsigned short* gB = Nb + (size_t)(rowB + row) * D_ + k0 + c * 8;
            __builtin_amdgcn_global_load_lds(
                (const __attribute__((address_space(1))) void*)gA,
                (__attribute__((address_space(3))) void*)(AsB + region * 1024), 16, 0, 0);
            __builtin_amdgcn_global_load_lds(
                (const __attribute__((address_space(1))) void*)gB,
                (__attribute__((address_space(3))) void*)(BsB + region * 1024), 16, 0, 0);
        }
        __syncthreads();
        // compute: 2 mfma-K groups x 4 mfma (wave quadrant = 32 rows x 32 cols)
#pragma unroll
        for (int kk = 0; kk < 2; kk++) {
            int pc = (kk * 4 + quad) ^ l7;   // swizzled chunk (rows == l15 mod 8 -> ^l7)
            bf16x8 a[2], b[2];
#pragma unroll
            for (int t = 0; t < 2; t++) {
                int rA = wr * 32 + t * 16 + l15;
                a[t] = *(const bf16x8*)(AsB + rA * 128 + pc * 16);
                int rB = wc * 32 + t * 16 + l15;
                b[t] = *(const bf16x8*)(BsB + rB * 128 + pc * 16);
            }
#pragma unroll
            for (int i = 0; i < 2; i++)
#pragma unroll
                for (int j = 0; j < 2; j++)
                    accf[i][j] = __builtin_amdgcn_mfma_f32_16x16x32_bf16(a[i], b[j], accf[i][j], 0, 0, 0);
        }
    }

    // ---------- epilogue ----------
    // C/D layout (16x16): col = lane&15, row = quad*4 + reg
    float t_sum = 0.0f, p_exp = 0.0f, p_s = 0.0f;
    int p_cnt = 0;
#pragma unroll
    for (int mt = 0; mt < 2; mt++) {
        int rbase = rowA + wr * 32 + mt * 16 + quad * 4;
        u64 al[4], ah[4]; int ac[4]; float ia[4];
#pragma unroll
        for (int r = 0; r < 4; r++) {
            al[r] = lo[rbase + r]; ah[r] = hi[rbase + r];
            ac[r] = cnt[rbase + r]; ia[r] = invs[rbase + r];
        }
#pragma unroll
        for (int nt = 0; nt < 2; nt++) {
#pragma unroll
            for (int r = 0; r < 4; r++) {
                float s = accf[mt][nt][r] * ia[r] * ib[nt];   // dot * inv_i*inv_j*10
                float es = __expf(s);
                t_sum += es;
                int inter = __popcll(al[r] & jl[nt]) + __popcll(ah[r] & jh[nt]);
                int uni = ac[r] + jc[nt] - inter;
                if ((10 * inter > 3 * uni) && (rbase + r != colg[nt])) {
                    p_exp += es; p_s += s; p_cnt++;
                }
            }
        }
    }

    // per-wave reduction, LDS combine, ONE uncontended store per block
#pragma unroll
    for (int off = 32; off > 0; off >>= 1) {
        t_sum += __shfl_down(t_sum, off);
        p_exp += __shfl_down(p_exp, off);
        p_s   += __shfl_down(p_s, off);
        p_cnt += __shfl_down(p_cnt, off);
    }
    if (lane == 0) { redT[w] = t_sum; redPe[w] = p_exp; redPs[w] = p_s; redC[w] = p_cnt; }
    __syncthreads();
    if (tid == 0) {
        double T = 0, Pe = 0, Ps = 0;
        long long C = 0;
        for (int i = 0; i < 4; i++) {
            T += (double)redT[i]; Pe += (double)redPe[i];
            Ps += (double)redPs[i]; C += redC[i];
        }
        double scale = (bi == bj) ? 1.0 : 2.0;   // symmetry: off-diagonal counts twice
        double* dst = partials + (size_t)blockIdx.x * 8;
        // agent-scope atomic stores: coherent at the device coherence point (cross-XCD safe)
        __hip_atomic_store(&dst[0], T * scale,  __ATOMIC_RELAXED, __HIP_MEMORY_SCOPE_AGENT);
        __hip_atomic_store(&dst[1], Pe * scale, __ATOMIC_RELAXED, __HIP_MEMORY_SCOPE_AGENT);
        __hip_atomic_store(&dst[2], Ps * scale, __ATOMIC_RELAXED, __HIP_MEMORY_SCOPE_AGENT);
        __hip_atomic_store(&dst[3], (double)C * scale, __ATOMIC_RELAXED, __HIP_MEMORY_SCOPE_AGENT);
        // acq_rel RMW: release half orders the four stores above before the counter bump
        unsigned int old = __hip_atomic_fetch_add(done, 1u, __ATOMIC_ACQ_REL, __HIP_MEMORY_SCOPE_AGENT);
        isLast = (old == (unsigned int)(NBLK - 1)) ? 1 : 0;
    }
    __syncthreads();

    // ---------- last block reduces all partials and writes the loss ----------
    if (isLast) {
        __builtin_amdgcn_fence(__ATOMIC_ACQUIRE, "agent");   // pair with producers' release
        double T = 0, Pe = 0, Ps = 0, C = 0;
        for (int i = tid; i < NBLK; i += 256) {
            const double* src = partials + (size_t)i * 8;
            T  += __hip_atomic_load(&src[0], __ATOMIC_RELAXED, __HIP_MEMORY_SCOPE_AGENT);
            Pe += __hip_atomic_load(&src[1], __ATOMIC_RELAXED, __HIP_MEMORY_SCOPE_AGENT);
            Ps += __hip_atomic_load(&src[2], __ATOMIC_RELAXED, __HIP_MEMORY_SCOPE_AGENT);
            C  += __hip_atomic_load(&src[3], __ATOMIC_RELAXED, __HIP_MEMORY_SCOPE_AGENT);
        }
#pragma unroll
        for (int off = 32; off > 0; off >>= 1) {
            T += __shfl_down(T, off);
            Pe += __shfl_down(Pe, off);
            Ps += __shfl_down(Ps, off);
            C += __shfl_down(C, off);
        }
        __shared__ double frT[4], frPe[4], frPs[4], frC[4];
        if (lane == 0) { frT[w] = T; frPe[w] = Pe; frPs[w] = Ps; frC[w] = C; }
        __syncthreads();
        if (tid == 0) {
            double Tt = 0, Pet = 0, Pst = 0, n = 0;
            for (int i = 0; i < 4; i++) { Tt += frT[i]; Pet += frPe[i]; Pst += frPs[i]; n += frC[i]; }
            double neg = Tt - Pet;   // negatives incl. diagonal
            double loss = (n > 0.0) ? log(neg) + (Pet / neg - Pst) / n : 0.0;
            out[0] = (float)loss;
        }
    }
}

extern "C" void kernel_launch(void* const* d_in, const int* in_sizes, int n_in,
                              void* d_out, int out_size, void* d_ws, size_t ws_size,
                              hipStream_t stream) {
    const float* rep = (const float*)d_in[0];
    const int* codes = (const int*)d_in[1];
    // d_in[2] = labels, unused by the reference computation

    // workspace layout
    unsigned short* nb = (unsigned short*)d_ws;                // 2 MiB raw bf16
    char* p = (char*)d_ws + (size_t)B_ * D_ * 2;
    float* invs = (float*)p;                                   // 16 KiB
    u64* lo = (u64*)(invs + B_);                               // 32 KiB
    u64* hi = lo + B_;                                         // 32 KiB
    int* cnt = (int*)(hi + B_);                                // 16 KiB
    double* partials = (double*)(cnt + B_);                    // 2080 x 8 doubles = 130 KiB
    unsigned int* done = (unsigned int*)(partials + (size_t)NBLK * 8);

    float* out = (float*)d_out;

    prep_kernel<<<B_ / 4, 256, 0, stream>>>(rep, codes, nb, invs, lo, hi, cnt, done);
    fused_kernel<<<NBLK, 256, 0, stream>>>(nb, invs, lo, hi, cnt, partials, done, out);
}

// Round 4
// 87.995 us; speedup vs baseline: 1.2369x; 1.2369x over previous
//
#include <hip/hip_runtime.h>
#include <hip/hip_bf16.h>
#include <cstdint>

#define B_ 4096
#define D_ 256
#define M_ 60
#define NT_ 64          // 64-tiles per dimension
#define NBLK 2080       // NT_*(NT_+1)/2 upper-triangle tiles
#define BM 64

typedef unsigned long long u64;
typedef short bf16x8 __attribute__((ext_vector_type(8)));   // 8 bf16 = 4 VGPRs
typedef float f32x4 __attribute__((ext_vector_type(4)));

__device__ __forceinline__ unsigned short f2bf(float x) {
    __hip_bfloat16 b = __float2bfloat16(x);
    return __builtin_bit_cast(unsigned short, b);
}

// ---------- prep: bf16 cast of raw rep, inv-norm*sqrt(10), code masks (coalesced, once) ----------
__global__ __launch_bounds__(256) void prep_kernel(
    const float* __restrict__ rep, const int* __restrict__ codes,
    unsigned short* __restrict__ nb, float* __restrict__ invs,
    u64* __restrict__ lo, u64* __restrict__ hi, int* __restrict__ cnt) {
    const int w = threadIdx.x >> 6;
    const int lane = threadIdx.x & 63;
    const int row = blockIdx.x * 4 + w;

    float4 v = ((const float4*)(rep + (size_t)row * D_))[lane];
    float ss = v.x * v.x + v.y * v.y + v.z * v.z + v.w * v.w;
#pragma unroll
    for (int off = 32; off > 0; off >>= 1) ss += __shfl_down(ss, off);
    ss = __shfl(ss, 0);

    // store RAW bf16 (normalization folded into epilogue scale)
    ushort4 o;
    o.x = f2bf(v.x); o.y = f2bf(v.y); o.z = f2bf(v.z); o.w = f2bf(v.w);
    ((ushort4*)(nb + (size_t)row * D_))[lane] = o;

    // code membership mask via wave-OR reduction
    u64 l = 0, h = 0;
    if (lane < M_) {
        int c = codes[row * M_ + lane];
        if (c < 64) l = 1ull << c;
        else        h = 1ull << (c - 64);
    }
#pragma unroll
    for (int off = 32; off > 0; off >>= 1) {
        l |= __shfl_down(l, off);
        h |= __shfl_down(h, off);
    }
    if (lane == 0) {
        invs[row] = (1.0f / sqrtf(ss)) * 3.16227766016838f;  // inv_norm * sqrt(1/T)
        lo[row] = l; hi[row] = h;
        cnt[row] = __popcll(l) + __popcll(h);
    }
}

// ---------- fused: 64x64 tiles, SINGLE-SHOT full-K staging (one latency round) ----------
// LDS: A 64x256 bf16 (32 KB) + B 64x256 bf16 (32 KB). One vmcnt drain + one barrier,
// then 8 K-groups x 4 MFMA per wave. Wave w owns 32x32 quadrant (wr=w>>1, wc=w&1).
// Cross-block results go through plain stores + a separate finalize kernel — the
// kernel boundary provides coherence (R3 lesson: per-block agent fences thrash L2).
__global__ __launch_bounds__(256) void fused_kernel(
    const unsigned short* __restrict__ Nb, const float* __restrict__ invs,
    const u64* __restrict__ lo, const u64* __restrict__ hi, const int* __restrict__ cnt,
    double* __restrict__ partials /* NBLK x 8 doubles (64B stride) */) {
    __shared__ __attribute__((aligned(16))) char AsB[BM * 512];   // 32 KB, 512 B/row
    __shared__ __attribute__((aligned(16))) char BsB[BM * 512];   // 32 KB
    __shared__ float redT[4], redPe[4], redPs[4];
    __shared__ int redC[4];

    const int tid = threadIdx.x;
    const int lane = tid & 63;
    const int w = tid >> 6;          // 0..3
    const int wr = w >> 1, wc = w & 1;
    const int quad = lane >> 4;
    const int l15 = lane & 15;
    const int l7 = lane & 7;

    // block -> (bi, bj) with bj >= bi
    int q = blockIdx.x, bi = 0;
    while (q >= NT_ - bi) { q -= NT_ - bi; bi++; }
    const int bj = bi + q;
    const int rowA = bi * BM, rowB = bj * BM;

    // ---- stage both tiles in ONE shot: 32 regions x 1024 B per operand ----
    // physical chunk P = region*64 + lane (0..2047); row = P>>5, pc = P&31,
    // logical chunk c = pc ^ (row&7)  (XOR on low 3 bits only; bijective per row)
#pragma unroll
    for (int it = 0; it < 8; it++) {
        int region = it * 4 + w;          // 0..31
        int P = region * 64 + lane;       // 0..2047
        int row = P >> 5;
        int c = (P & 31) ^ (row & 7);
        const unsigned short* gA = Nb + (size_t)(rowA + row) * D_ + c * 8;
        const unsigned short* gB = Nb + (size_t)(rowB + row) * D_ + c * 8;
        __builtin_amdgcn_global_load_lds(
            (const __attribute__((address_space(1))) void*)gA,
            (__attribute__((address_space(3))) void*)(AsB + region * 1024), 16, 0, 0);
        __builtin_amdgcn_global_load_lds(
            (const __attribute__((address_space(1))) void*)gB,
            (__attribute__((address_space(3))) void*)(BsB + region * 1024), 16, 0, 0);
    }

    // ---- hoist ALL epilogue metadata loads under the staging latency ----
    int colg[2]; u64 jl[2], jh[2]; int jc[2]; float ib[2];
#pragma unroll
    for (int nt = 0; nt < 2; nt++) {
        int cg = rowB + wc * 32 + nt * 16 + l15;
        colg[nt] = cg; jl[nt] = lo[cg]; jh[nt] = hi[cg]; jc[nt] = cnt[cg];
        ib[nt] = invs[cg];
    }
    u64 al[2][4], ah[2][4]; int ac[2][4]; float ia[2][4];
#pragma unroll
    for (int mt = 0; mt < 2; mt++) {
        int rbase = rowA + wr * 32 + mt * 16 + quad * 4;
#pragma unroll
        for (int r = 0; r < 4; r++) {
            al[mt][r] = lo[rbase + r]; ah[mt][r] = hi[rbase + r];
            ac[mt][r] = cnt[rbase + r]; ia[mt][r] = invs[rbase + r];
        }
    }

    __syncthreads();   // drains vmcnt: LDS tiles complete

    // ---- compute: 8 K-groups x 4 MFMA (wave quadrant = 32 rows x 32 cols) ----
    f32x4 accf[2][2] = {};
#pragma unroll
    for (int kk = 0; kk < 8; kk++) {
        int pc = (kk * 4 + quad) ^ l7;   // swizzled 16B chunk (XOR affects low 3 bits)
        bf16x8 a[2], b[2];
#pragma unroll
        for (int t = 0; t < 2; t++) {
            int rA = wr * 32 + t * 16 + l15;
            a[t] = *(const bf16x8*)(AsB + rA * 512 + pc * 16);
            int rB = wc * 32 + t * 16 + l15;
            b[t] = *(const bf16x8*)(BsB + rB * 512 + pc * 16);
        }
#pragma unroll
        for (int i = 0; i < 2; i++)
#pragma unroll
            for (int j = 0; j < 2; j++)
                accf[i][j] = __builtin_amdgcn_mfma_f32_16x16x32_bf16(a[i], b[j], accf[i][j], 0, 0, 0);
    }

    // ---------- epilogue ----------
    // C/D layout (16x16): col = lane&15, row = quad*4 + reg
    float t_sum = 0.0f, p_exp = 0.0f, p_s = 0.0f;
    int p_cnt = 0;
#pragma unroll
    for (int mt = 0; mt < 2; mt++) {
        int rbase = rowA + wr * 32 + mt * 16 + quad * 4;
#pragma unroll
        for (int nt = 0; nt < 2; nt++) {
#pragma unroll
            for (int r = 0; r < 4; r++) {
                float s = accf[mt][nt][r] * ia[mt][r] * ib[nt];   // dot * inv_i*inv_j*10
                float es = __expf(s);
                t_sum += es;
                int inter = __popcll(al[mt][r] & jl[nt]) + __popcll(ah[mt][r] & jh[nt]);
                int uni = ac[mt][r] + jc[nt] - inter;
                if ((10 * inter > 3 * uni) && (rbase + r != colg[nt])) {
                    p_exp += es; p_s += s; p_cnt++;
                }
            }
        }
    }

    // per-wave reduction, LDS combine, ONE uncontended store per block
#pragma unroll
    for (int off = 32; off > 0; off >>= 1) {
        t_sum += __shfl_down(t_sum, off);
        p_exp += __shfl_down(p_exp, off);
        p_s   += __shfl_down(p_s, off);
        p_cnt += __shfl_down(p_cnt, off);
    }
    if (lane == 0) { redT[w] = t_sum; redPe[w] = p_exp; redPs[w] = p_s; redC[w] = p_cnt; }
    __syncthreads();
    if (tid == 0) {
        double T = 0, Pe = 0, Ps = 0;
        long long C = 0;
        for (int i = 0; i < 4; i++) {
            T += (double)redT[i]; Pe += (double)redPe[i];
            Ps += (double)redPs[i]; C += redC[i];
        }
        double scale = (bi == bj) ? 1.0 : 2.0;   // symmetry: off-diagonal counts twice
        double* dst = partials + (size_t)blockIdx.x * 8;
        dst[0] = T * scale;
        dst[1] = Pe * scale;
        dst[2] = Ps * scale;
        dst[3] = (double)C * scale;
    }
}

// ---------- finalize: reduce 2080 partials, compute loss ----------
__global__ __launch_bounds__(256) void finalize_kernel(
    const double* __restrict__ partials, float* __restrict__ out) {
    const int tid = threadIdx.x;
    const int lane = tid & 63;
    const int w = tid >> 6;
    double T = 0, Pe = 0, Ps = 0, C = 0;
    for (int i = tid; i < NBLK; i += 256) {
        const double* src = partials + (size_t)i * 8;
        T += src[0]; Pe += src[1]; Ps += src[2]; C += src[3];
    }
#pragma unroll
    for (int off = 32; off > 0; off >>= 1) {
        T += __shfl_down(T, off);
        Pe += __shfl_down(Pe, off);
        Ps += __shfl_down(Ps, off);
        C += __shfl_down(C, off);
    }
    __shared__ double redT[4], redPe[4], redPs[4], redC[4];
    if (lane == 0) { redT[w] = T; redPe[w] = Pe; redPs[w] = Ps; redC[w] = C; }
    __syncthreads();
    if (tid == 0) {
        double Tt = 0, Pet = 0, Pst = 0, n = 0;
        for (int i = 0; i < 4; i++) { Tt += redT[i]; Pet += redPe[i]; Pst += redPs[i]; n += redC[i]; }
        double neg = Tt - Pet;   // negatives incl. diagonal
        double loss = (n > 0.0) ? log(neg) + (Pet / neg - Pst) / n : 0.0;
        out[0] = (float)loss;
    }
}

extern "C" void kernel_launch(void* const* d_in, const int* in_sizes, int n_in,
                              void* d_out, int out_size, void* d_ws, size_t ws_size,
                              hipStream_t stream) {
    const float* rep = (const float*)d_in[0];
    const int* codes = (const int*)d_in[1];
    // d_in[2] = labels, unused by the reference computation

    // workspace layout
    unsigned short* nb = (unsigned short*)d_ws;                // 2 MiB raw bf16
    char* p = (char*)d_ws + (size_t)B_ * D_ * 2;
    float* invs = (float*)p;                                   // 16 KiB
    u64* lo = (u64*)(invs + B_);                               // 32 KiB
    u64* hi = lo + B_;                                         // 32 KiB
    int* cnt = (int*)(hi + B_);                                // 16 KiB
    double* partials = (double*)(cnt + B_);                    // 2080 x 8 doubles = 130 KiB

    float* out = (float*)d_out;

    prep_kernel<<<B_ / 4, 256, 0, stream>>>(rep, codes, nb, invs, lo, hi, cnt);
    fused_kernel<<<NBLK, 256, 0, stream>>>(nb, invs, lo, hi, cnt, partials);
    finalize_kernel<<<1, 256, 0, stream>>>(partials, out);
}

// Round 9
// 83.025 us; speedup vs baseline: 1.3110x; 1.0599x over previous
//
#include <hip/hip_runtime.h>
#include <hip/hip_bf16.h>
#include <cstdint>

#define B_ 4096
#define D_ 256
#define M_ 60
#define NT_ 32          // 128-tiles per dimension
#define NBLK 528        // NT_*(NT_+1)/2 upper-triangle tiles
#define BM 128
#define BK 64           // bf16 elements per K-step (128 bytes/row)

typedef unsigned long long u64;
typedef short bf16x8 __attribute__((ext_vector_type(8)));   // 8 bf16 = 4 VGPRs
typedef float f32x4 __attribute__((ext_vector_type(4)));

__device__ __forceinline__ unsigned short f2bf(float x) {
    __hip_bfloat16 b = __float2bfloat16(x);
    return __builtin_bit_cast(unsigned short, b);
}

// ---------- prep: bf16 cast of raw rep, inv-norm*sqrt(10), code masks (coalesced, once) ----------
__global__ __launch_bounds__(256) void prep_kernel(
    const float* __restrict__ rep, const int* __restrict__ codes,
    unsigned short* __restrict__ nb, float* __restrict__ invs,
    u64* __restrict__ lo, u64* __restrict__ hi, int* __restrict__ cnt) {
    const int w = threadIdx.x >> 6;
    const int lane = threadIdx.x & 63;
    const int row = blockIdx.x * 4 + w;

    float4 v = ((const float4*)(rep + (size_t)row * D_))[lane];
    float ss = v.x * v.x + v.y * v.y + v.z * v.z + v.w * v.w;
#pragma unroll
    for (int off = 32; off > 0; off >>= 1) ss += __shfl_down(ss, off);
    ss = __shfl(ss, 0);

    // store RAW bf16 (normalization folded into epilogue scale)
    ushort4 o;
    o.x = f2bf(v.x); o.y = f2bf(v.y); o.z = f2bf(v.z); o.w = f2bf(v.w);
    ((ushort4*)(nb + (size_t)row * D_))[lane] = o;

    // code membership mask via wave-OR reduction
    u64 l = 0, h = 0;
    if (lane < M_) {
        int c = codes[row * M_ + lane];
        if (c < 64) l = 1ull << c;
        else        h = 1ull << (c - 64);
    }
#pragma unroll
    for (int off = 32; off > 0; off >>= 1) {
        l |= __shfl_down(l, off);
        h |= __shfl_down(h, off);
    }
    if (lane == 0) {
        invs[row] = (1.0f / sqrtf(ss)) * 3.16227766016838f;  // inv_norm * sqrt(1/T)
        lo[row] = l; hi[row] = h;
        cnt[row] = __popcll(l) + __popcll(h);
    }
}

// ---------- fused: 128x128 tiles, 528 blocks, 2-phase double-buffered staging ----------
// Wave w owns a 64x64 quadrant (wr=w>>1, wc=w&1); per wave 4x4 grid of 16x16 accs.
// LDS: A/B tiles 2 x (128x64 bf16 = 16 KB) dbuf = 64 KB + 6 KB metadata -> 2 blocks/CU.
// K-loop: stage(t+1) issued BEFORE compute(t); one vmcnt-drain+barrier per step (T3 2-phase).
// Halves L2 traffic vs 64-tiles (528x128KB=68MB vs 2080x64KB=136MB), 4x fewer epilogues.
__global__ __launch_bounds__(256) void fused_kernel(
    const unsigned short* __restrict__ Nb, const float* __restrict__ invs,
    const u64* __restrict__ lo, const u64* __restrict__ hi, const int* __restrict__ cnt,
    double* __restrict__ partials /* NBLK x 8 doubles (64B stride) */) {
    __shared__ __attribute__((aligned(16))) char AsB[2 * BM * BK * 2];   // 32 KB (2 bufs)
    __shared__ __attribute__((aligned(16))) char BsB[2 * BM * BK * 2];   // 32 KB
    __shared__ u64 mLo[256], mHi[256];       // [0..127]=A rows, [128..255]=B cols
    __shared__ int mCnt[256];
    __shared__ float mInv[256];
    __shared__ float redT[4], redPe[4], redPs[4];
    __shared__ int redC[4];

    const int tid = threadIdx.x;
    const int lane = tid & 63;
    const int w = tid >> 6;          // 0..3
    const int wr = w >> 1, wc = w & 1;
    const int quad = lane >> 4;
    const int l15 = lane & 15;
    const int l7 = lane & 7;

    // block -> (bi, bj) with bj >= bi
    int q = blockIdx.x, bi = 0;
    while (q >= NT_ - bi) { q -= NT_ - bi; bi++; }
    const int bj = bi + q;
    const int rowA = bi * BM, rowB = bj * BM;

    // stage one K-step (16 KB per operand = 16 regions x 1024 B each)
    // physical chunk P = region*64 + lane (0..1023); row = P>>3, c = (P&7) ^ (row&7)
    auto STAGE = [&](int t, int buf) {
        const int k0 = t * BK;
#pragma unroll
        for (int it = 0; it < 4; it++) {
            int region = it * 4 + w;          // 0..15
            int P = region * 64 + lane;       // 0..1023
            int row = P >> 3;
            int c = (P & 7) ^ (row & 7);
            const unsigned short* gA = Nb + (size_t)(rowA + row) * D_ + k0 + c * 8;
            const unsigned short* gB = Nb + (size_t)(rowB + row) * D_ + k0 + c * 8;
            __builtin_amdgcn_global_load_lds(
                (const __attribute__((address_space(1))) void*)gA,
                (__attribute__((address_space(3))) void*)(AsB + buf * 16384 + region * 1024), 16, 0, 0);
            __builtin_amdgcn_global_load_lds(
                (const __attribute__((address_space(1))) void*)gB,
                (__attribute__((address_space(3))) void*)(BsB + buf * 16384 + region * 1024), 16, 0, 0);
        }
    };

    // prologue: stage step 0, then metadata->LDS (latency hides under the staging drain)
    STAGE(0, 0);
    if (tid < 128) {
        int g = rowA + tid;
        mLo[tid] = lo[g]; mHi[tid] = hi[g]; mCnt[tid] = cnt[g]; mInv[tid] = invs[g];
    } else {
        int g = rowB + (tid - 128);
        mLo[tid] = lo[g]; mHi[tid] = hi[g]; mCnt[tid] = cnt[g]; mInv[tid] = invs[g];
    }
    __syncthreads();   // drains vmcnt (tiles) + lgkmcnt (meta ds_writes)

    // ---- 2-phase K-loop: 4 steps of BK=64 ----
    f32x4 accf[4][4] = {};
    for (int t = 0; t < 4; t++) {
        const int cur = t & 1;
        if (t < 3) STAGE(t + 1, cur ^ 1);    // issue next-step loads before compute
#pragma unroll
        for (int kk = 0; kk < 2; kk++) {
            const int pc = (kk * 4 + quad) ^ l7;   // swizzled 16B chunk
            bf16x8 a[4], b[4];
#pragma unroll
            for (int i = 0; i < 4; i++) {
                int rA = wr * 64 + i * 16 + l15;
                a[i] = *(const bf16x8*)(AsB + cur * 16384 + rA * 128 + pc * 16);
                int rB = wc * 64 + i * 16 + l15;
                b[i] = *(const bf16x8*)(BsB + cur * 16384 + rB * 128 + pc * 16);
            }
#pragma unroll
            for (int i = 0; i < 4; i++)
#pragma unroll
                for (int j = 0; j < 4; j++)
                    accf[i][j] = __builtin_amdgcn_mfma_f32_16x16x32_bf16(a[i], b[j], accf[i][j], 0, 0, 0);
        }
        __syncthreads();   // drains vmcnt (next-step loads done) + barrier (buffer handoff)
    }

    // ---------- epilogue ----------
    // C/D layout (16x16): col = lane&15, row = quad*4 + reg
    // col-side metadata hoisted once (4 j-tiles)
    u64 jl[4], jh[4]; int jc[4]; float ibv[4]; int cglob[4];
#pragma unroll
    for (int j = 0; j < 4; j++) {
        int cloc = wc * 64 + j * 16 + l15;
        jl[j] = mLo[128 + cloc]; jh[j] = mHi[128 + cloc];
        jc[j] = mCnt[128 + cloc]; ibv[j] = mInv[128 + cloc];
        cglob[j] = rowB + cloc;
    }

    float t_sum = 0.0f, p_exp = 0.0f, p_s = 0.0f;
    int p_cnt = 0;
#pragma unroll
    for (int i = 0; i < 4; i++) {
        int rloc = wr * 64 + i * 16 + quad * 4;
        u64 al[4], ah[4]; int ac[4]; float ia[4];
#pragma unroll
        for (int r = 0; r < 4; r++) {
            al[r] = mLo[rloc + r]; ah[r] = mHi[rloc + r];
            ac[r] = mCnt[rloc + r]; ia[r] = mInv[rloc + r];
        }
        int rglob = rowA + rloc;
#pragma unroll
        for (int j = 0; j < 4; j++) {
#pragma unroll
            for (int r = 0; r < 4; r++) {
                float s = accf[i][j][r] * ia[r] * ibv[j];   // dot * inv_i*inv_j*10
                float es = __expf(s);
                t_sum += es;
                int inter = __popcll(al[r] & jl[j]) + __popcll(ah[r] & jh[j]);
                int uni = ac[r] + jc[j] - inter;
                if ((10 * inter > 3 * uni) && (rglob + r != cglob[j])) {
                    p_exp += es; p_s += s; p_cnt++;
                }
            }
        }
    }

    // per-wave reduction, LDS combine, ONE uncontended store per block
#pragma unroll
    for (int off = 32; off > 0; off >>= 1) {
        t_sum += __shfl_down(t_sum, off);
        p_exp += __shfl_down(p_exp, off);
        p_s   += __shfl_down(p_s, off);
        p_cnt += __shfl_down(p_cnt, off);
    }
    if (lane == 0) { redT[w] = t_sum; redPe[w] = p_exp; redPs[w] = p_s; redC[w] = p_cnt; }
    __syncthreads();
    if (tid == 0) {
        double T = 0, Pe = 0, Ps = 0;
        long long C = 0;
        for (int i = 0; i < 4; i++) {
            T += (double)redT[i]; Pe += (double)redPe[i];
            Ps += (double)redPs[i]; C += redC[i];
        }
        double scale = (bi == bj) ? 1.0 : 2.0;   // symmetry: off-diagonal counts twice
        double* dst = partials + (size_t)blockIdx.x * 8;
        dst[0] = T * scale;
        dst[1] = Pe * scale;
        dst[2] = Ps * scale;
        dst[3] = (double)C * scale;
    }
}

// ---------- finalize: reduce 528 partials, compute loss ----------
__global__ __launch_bounds__(256) void finalize_kernel(
    const double* __restrict__ partials, float* __restrict__ out) {
    const int tid = threadIdx.x;
    const int lane = tid & 63;
    const int w = tid >> 6;
    double T = 0, Pe = 0, Ps = 0, C = 0;
    for (int i = tid; i < NBLK; i += 256) {
        const double* src = partials + (size_t)i * 8;
        T += src[0]; Pe += src[1]; Ps += src[2]; C += src[3];
    }
#pragma unroll
    for (int off = 32; off > 0; off >>= 1) {
        T += __shfl_down(T, off);
        Pe += __shfl_down(Pe, off);
        Ps += __shfl_down(Ps, off);
        C += __shfl_down(C, off);
    }
    __shared__ double redT[4], redPe[4], redPs[4], redC[4];
    if (lane == 0) { redT[w] = T; redPe[w] = Pe; redPs[w] = Ps; redC[w] = C; }
    __syncthreads();
    if (tid == 0) {
        double Tt = 0, Pet = 0, Pst = 0, n = 0;
        for (int i = 0; i < 4; i++) { Tt += redT[i]; Pet += redPe[i]; Pst += redPs[i]; n += redC[i]; }
        double neg = Tt - Pet;   // negatives incl. diagonal
        double loss = (n > 0.0) ? log(neg) + (Pet / neg - Pst) / n : 0.0;
        out[0] = (float)loss;
    }
}

extern "C" void kernel_launch(void* const* d_in, const int* in_sizes, int n_in,
                              void* d_out, int out_size, void* d_ws, size_t ws_size,
                              hipStream_t stream) {
    const float* rep = (const float*)d_in[0];
    const int* codes = (const int*)d_in[1];
    // d_in[2] = labels, unused by the reference computation

    // workspace layout
    unsigned short* nb = (unsigned short*)d_ws;                // 2 MiB raw bf16
    char* p = (char*)d_ws + (size_t)B_ * D_ * 2;
    float* invs = (float*)p;                                   // 16 KiB
    u64* lo = (u64*)(invs + B_);                               // 32 KiB
    u64* hi = lo + B_;                                         // 32 KiB
    int* cnt = (int*)(hi + B_);                                // 16 KiB
    double* partials = (double*)(cnt + B_);                    // 528 x 8 doubles

    float* out = (float*)d_out;

    prep_kernel<<<B_ / 4, 256, 0, stream>>>(rep, codes, nb, invs, lo, hi, cnt);
    fused_kernel<<<NBLK, 256, 0, stream>>>(nb, invs, lo, hi, cnt, partials);
    finalize_kernel<<<1, 256, 0, stream>>>(partials, out);
}

// Round 12
// 81.038 us; speedup vs baseline: 1.3431x; 1.0245x over previous
//
#include <hip/hip_runtime.h>
#include <hip/hip_bf16.h>
#include <cstdint>

#define B_ 4096
#define D_ 256
#define M_ 60
#define NT_ 32          // 128-tiles per dimension
#define NBLK 528        // NT_*(NT_+1)/2 upper-triangle tiles; 528 = 8 XCDs * 66 (bijective swizzle)
#define BM 128
#define BK 64           // bf16 elements per K-step (128 bytes/row)

typedef unsigned long long u64;
typedef short bf16x8 __attribute__((ext_vector_type(8)));   // 8 bf16 = 4 VGPRs
typedef float f32x4 __attribute__((ext_vector_type(4)));

__device__ __forceinline__ unsigned short f2bf(float x) {
    __hip_bfloat16 b = __float2bfloat16(x);
    return __builtin_bit_cast(unsigned short, b);
}

// ---------- prep: bf16 cast of raw rep, inv-norm*sqrt(10), code masks (coalesced, once) ----------
__global__ __launch_bounds__(256) void prep_kernel(
    const float* __restrict__ rep, const int* __restrict__ codes,
    unsigned short* __restrict__ nb, float* __restrict__ invs,
    u64* __restrict__ lo, u64* __restrict__ hi, int* __restrict__ cnt) {
    const int w = threadIdx.x >> 6;
    const int lane = threadIdx.x & 63;
    const int row = blockIdx.x * 4 + w;

    float4 v = ((const float4*)(rep + (size_t)row * D_))[lane];
    float ss = v.x * v.x + v.y * v.y + v.z * v.z + v.w * v.w;
#pragma unroll
    for (int off = 32; off > 0; off >>= 1) ss += __shfl_down(ss, off);
    ss = __shfl(ss, 0);

    // store RAW bf16 (normalization folded into epilogue scale)
    ushort4 o;
    o.x = f2bf(v.x); o.y = f2bf(v.y); o.z = f2bf(v.z); o.w = f2bf(v.w);
    ((ushort4*)(nb + (size_t)row * D_))[lane] = o;

    // code membership mask via wave-OR reduction
    u64 l = 0, h = 0;
    if (lane < M_) {
        int c = codes[row * M_ + lane];
        if (c < 64) l = 1ull << c;
        else        h = 1ull << (c - 64);
    }
#pragma unroll
    for (int off = 32; off > 0; off >>= 1) {
        l |= __shfl_down(l, off);
        h |= __shfl_down(h, off);
    }
    if (lane == 0) {
        invs[row] = (1.0f / sqrtf(ss)) * 3.16227766016838f;  // inv_norm * sqrt(1/T)
        lo[row] = l; hi[row] = h;
        cnt[row] = __popcll(l) + __popcll(h);
    }
}

// ---------- fused: 128x128 tiles, 512 threads (8 waves), 2-phase dbuf, XCD swizzle ----------
// R9 post-mortem: 256-thr version had only 8 waves/CU (latency-bound, ~22us); R0's 64-tile
// version was L3-BW-bound (~136MB @ ~6.5TB/s = 22us). This version keeps 128-tile traffic
// (68MB) AND raises TLP to 16 waves/CU: 8 waves/block, each owning a 64x32 sub-tile
// (wr=w>>2 row half, wc=w&3 col quarter; acc 4x2 of 16x16 = 32 VGPR).
// __launch_bounds__(512,4) caps VGPR at 128 so 2 blocks/CU (70KB LDS) fit.
// XCD swizzle: 528 = 8*66 exact -> swz=(bid&7)*66+(bid>>3) bijective; consecutive
// bi-panels share an XCD's L2 (A-panel reuse becomes L2 hits instead of L3).
__global__ __launch_bounds__(512, 4) void fused_kernel(
    const unsigned short* __restrict__ Nb, const float* __restrict__ invs,
    const u64* __restrict__ lo, const u64* __restrict__ hi, const int* __restrict__ cnt,
    double* __restrict__ partials /* NBLK x 8 doubles (64B stride) */) {
    __shared__ __attribute__((aligned(16))) char AsB[2 * BM * BK * 2];   // 32 KB (2 bufs)
    __shared__ __attribute__((aligned(16))) char BsB[2 * BM * BK * 2];   // 32 KB
    __shared__ u64 mLo[256], mHi[256];       // [0..127]=A rows, [128..255]=B cols
    __shared__ int mCnt[256];
    __shared__ float mInv[256];
    __shared__ float redT[8], redPe[8], redPs[8];
    __shared__ int redC[8];

    const int tid = threadIdx.x;
    const int lane = tid & 63;
    const int w = tid >> 6;          // 0..7
    const int wr = w >> 2, wc = w & 3;   // wave -> 64x32 sub-tile
    const int quad = lane >> 4;
    const int l15 = lane & 15;
    const int l7 = lane & 7;

    // XCD-aware bijective swizzle (528 = 8*66), then -> (bi, bj) with bj >= bi
    const int bid = blockIdx.x;
    const int swz = (bid & 7) * 66 + (bid >> 3);
    int q = swz, bi = 0;
    while (q >= NT_ - bi) { q -= NT_ - bi; bi++; }
    const int bj = bi + q;
    const int rowA = bi * BM, rowB = bj * BM;

    // stage one K-step (16 KB per operand = 16 regions x 1024 B each); 8 waves x 2 regions
    // physical chunk P = region*64 + lane (0..1023); row = P>>3, c = (P&7) ^ (row&7)
    auto STAGE = [&](int t, int buf) {
        const int k0 = t * BK;
#pragma unroll
        for (int it = 0; it < 2; it++) {
            int region = it * 8 + w;          // 0..15
            int P = region * 64 + lane;       // 0..1023
            int row = P >> 3;
            int c = (P & 7) ^ (row & 7);
            const unsigned short* gA = Nb + (size_t)(rowA + row) * D_ + k0 + c * 8;
            const unsigned short* gB = Nb + (size_t)(rowB + row) * D_ + k0 + c * 8;
            __builtin_amdgcn_global_load_lds(
                (const __attribute__((address_space(1))) void*)gA,
                (__attribute__((address_space(3))) void*)(AsB + buf * 16384 + region * 1024), 16, 0, 0);
            __builtin_amdgcn_global_load_lds(
                (const __attribute__((address_space(1))) void*)gB,
                (__attribute__((address_space(3))) void*)(BsB + buf * 16384 + region * 1024), 16, 0, 0);
        }
    };

    // prologue: stage step 0, then metadata->LDS (latency hides under the staging drain)
    STAGE(0, 0);
    if (tid < 128) {
        int g = rowA + tid;
        mLo[tid] = lo[g]; mHi[tid] = hi[g]; mCnt[tid] = cnt[g]; mInv[tid] = invs[g];
    } else if (tid < 256) {
        int t2 = tid - 128;
        int g = rowB + t2;
        mLo[128 + t2] = lo[g]; mHi[128 + t2] = hi[g]; mCnt[128 + t2] = cnt[g]; mInv[128 + t2] = invs[g];
    }
    __syncthreads();   // drains vmcnt (tiles) + lgkmcnt (meta ds_writes)

    // ---- 2-phase K-loop: 4 steps of BK=64 ----
    f32x4 accf[4][2] = {};
    for (int t = 0; t < 4; t++) {
        const int cur = t & 1;
        if (t < 3) STAGE(t + 1, cur ^ 1);    // issue next-step loads before compute
#pragma unroll
        for (int kk = 0; kk < 2; kk++) {
            const int pc = (kk * 4 + quad) ^ l7;   // swizzled 16B chunk
            bf16x8 a[4], b[2];
#pragma unroll
            for (int i = 0; i < 4; i++) {
                int rA = wr * 64 + i * 16 + l15;
                a[i] = *(const bf16x8*)(AsB + cur * 16384 + rA * 128 + pc * 16);
            }
#pragma unroll
            for (int j = 0; j < 2; j++) {
                int rB = wc * 32 + j * 16 + l15;
                b[j] = *(const bf16x8*)(BsB + cur * 16384 + rB * 128 + pc * 16);
            }
#pragma unroll
            for (int i = 0; i < 4; i++)
#pragma unroll
                for (int j = 0; j < 2; j++)
                    accf[i][j] = __builtin_amdgcn_mfma_f32_16x16x32_bf16(a[i], b[j], accf[i][j], 0, 0, 0);
        }
        __syncthreads();   // drains vmcnt (next-step loads done) + barrier (buffer handoff)
    }

    // ---------- epilogue ----------
    // C/D layout (16x16): col = lane&15, row = quad*4 + reg
    // col-side metadata hoisted once (2 j-tiles per wave)
    u64 jl[2], jh[2]; int jc[2]; float ibv[2]; int cglob[2];
#pragma unroll
    for (int j = 0; j < 2; j++) {
        int cloc = wc * 32 + j * 16 + l15;
        jl[j] = mLo[128 + cloc]; jh[j] = mHi[128 + cloc];
        jc[j] = mCnt[128 + cloc]; ibv[j] = mInv[128 + cloc];
        cglob[j] = rowB + cloc;
    }

    float t_sum = 0.0f, p_exp = 0.0f, p_s = 0.0f;
    int p_cnt = 0;
#pragma unroll
    for (int i = 0; i < 4; i++) {
        int rloc = wr * 64 + i * 16 + quad * 4;
        u64 al[4], ah[4]; int ac[4]; float ia[4];
#pragma unroll
        for (int r = 0; r < 4; r++) {
            al[r] = mLo[rloc + r]; ah[r] = mHi[rloc + r];
            ac[r] = mCnt[rloc + r]; ia[r] = mInv[rloc + r];
        }
        int rglob = rowA + rloc;
#pragma unroll
        for (int j = 0; j < 2; j++) {
#pragma unroll
            for (int r = 0; r < 4; r++) {
                float s = accf[i][j][r] * ia[r] * ibv[j];   // dot * inv_i*inv_j*10
                float es = __expf(s);
                t_sum += es;
                int inter = __popcll(al[r] & jl[j]) + __popcll(ah[r] & jh[j]);
                int uni = ac[r] + jc[j] - inter;
                if ((10 * inter > 3 * uni) && (rglob + r != cglob[j])) {
                    p_exp += es; p_s += s; p_cnt++;
                }
            }
        }
    }

    // per-wave reduction, LDS combine, ONE uncontended store per block
#pragma unroll
    for (int off = 32; off > 0; off >>= 1) {
        t_sum += __shfl_down(t_sum, off);
        p_exp += __shfl_down(p_exp, off);
        p_s   += __shfl_down(p_s, off);
        p_cnt += __shfl_down(p_cnt, off);
    }
    if (lane == 0) { redT[w] = t_sum; redPe[w] = p_exp; redPs[w] = p_s; redC[w] = p_cnt; }
    __syncthreads();
    if (tid == 0) {
        double T = 0, Pe = 0, Ps = 0;
        long long C = 0;
        for (int i = 0; i < 8; i++) {
            T += (double)redT[i]; Pe += (double)redPe[i];
            Ps += (double)redPs[i]; C += redC[i];
        }
        double scale = (bi == bj) ? 1.0 : 2.0;   // symmetry: off-diagonal counts twice
        double* dst = partials + (size_t)swz * 8;
        dst[0] = T * scale;
        dst[1] = Pe * scale;
        dst[2] = Ps * scale;
        dst[3] = (double)C * scale;
    }
}

// ---------- finalize: reduce 528 partials, compute loss ----------
__global__ __launch_bounds__(256) void finalize_kernel(
    const double* __restrict__ partials, float* __restrict__ out) {
    const int tid = threadIdx.x;
    const int lane = tid & 63;
    const int w = tid >> 6;
    double T = 0, Pe = 0, Ps = 0, C = 0;
    for (int i = tid; i < NBLK; i += 256) {
        const double* src = partials + (size_t)i * 8;
        T += src[0]; Pe += src[1]; Ps += src[2]; C += src[3];
    }
#pragma unroll
    for (int off = 32; off > 0; off >>= 1) {
        T += __shfl_down(T, off);
        Pe += __shfl_down(Pe, off);
        Ps += __shfl_down(Ps, off);
        C += __shfl_down(C, off);
    }
    __shared__ double redT[4], redPe[4], redPs[4], redC[4];
    if (lane == 0) { redT[w] = T; redPe[w] = Pe; redPs[w] = Ps; redC[w] = C; }
    __syncthreads();
    if (tid == 0) {
        double Tt = 0, Pet = 0, Pst = 0, n = 0;
        for (int i = 0; i < 4; i++) { Tt += redT[i]; Pet += redPe[i]; Pst += redPs[i]; n += redC[i]; }
        double neg = Tt - Pet;   // negatives incl. diagonal
        double loss = (n > 0.0) ? log(neg) + (Pet / neg - Pst) / n : 0.0;
        out[0] = (float)loss;
    }
}

extern "C" void kernel_launch(void* const* d_in, const int* in_sizes, int n_in,
                              void* d_out, int out_size, void* d_ws, size_t ws_size,
                              hipStream_t stream) {
    const float* rep = (const float*)d_in[0];
    const int* codes = (const int*)d_in[1];
    // d_in[2] = labels, unused by the reference computation

    // workspace layout
    unsigned short* nb = (unsigned short*)d_ws;                // 2 MiB raw bf16
    char* p = (char*)d_ws + (size_t)B_ * D_ * 2;
    float* invs = (float*)p;                                   // 16 KiB
    u64* lo = (u64*)(invs + B_);                               // 32 KiB
    u64* hi = lo + B_;                                         // 32 KiB
    int* cnt = (int*)(hi + B_);                                // 16 KiB
    double* partials = (double*)(cnt + B_);                    // 528 x 8 doubles

    float* out = (float*)d_out;

    prep_kernel<<<B_ / 4, 256, 0, stream>>>(rep, codes, nb, invs, lo, hi, cnt);
    fused_kernel<<<NBLK, 512, 0, stream>>>(nb, invs, lo, hi, cnt, partials);
    finalize_kernel<<<1, 256, 0, stream>>>(partials, out);
}